// Round 6
// baseline (129.403 us; speedup 1.0000x reference)
//
#include <hip/hip_runtime.h>

#define B_ROWS   8192
#define BMASK    8191
#define DIM      128
#define BLK64    16384       // bytes per packed 64-row block (64*128*2)
#define NBLOCKS  1024

typedef __attribute__((ext_vector_type(8)))  __bf16 bf16x8;
typedef __attribute__((ext_vector_type(16))) float  f32x16;

// sqrt(log2(e)/0.07) folded symmetrically into both row normalizations.
#define RBSCALE 4.5398159f

// 64 rows per block: norm -> scale -> bf16 -> k-major packed layout
// packed[row>>6][granule=k/8][row&63][8 bf16]. Coalesced 256B store segments.
// Block 0 also zeroes the accumulators.
__global__ __launch_bounds__(256)
void prep_kernel(const float* __restrict__ e1, const float* __restrict__ e2,
                 char* __restrict__ p1, char* __restrict__ p2,
                 float* __restrict__ acc) {
    if (blockIdx.x == 0 && threadIdx.x < 4) acc[threadIdx.x] = 0.f;
    const int rb = blockIdx.x;            // 64-row block id, 0..255
    const float* src; char* dst; int rb_loc;
    if (rb < 128) { src = e1; dst = p1; rb_loc = rb; }
    else          { src = e2; dst = p2; rb_loc = rb - 128; }

    const int t  = threadIdx.x;
    const int rr = t >> 2;                // row within block, 0..63
    const int q  = t & 3;                 // quarter of the k-dim, 32 floats each

    const float* rp = src + (size_t)(rb_loc * 64 + rr) * DIM + q * 32;
    float4 f[8];
    float ss = 0.f;
#pragma unroll
    for (int j = 0; j < 8; ++j) {
        f[j] = ((const float4*)rp)[j];
        ss += f[j].x * f[j].x + f[j].y * f[j].y + f[j].z * f[j].z + f[j].w * f[j].w;
    }
    // quad reduce: lanes 4r..4r+3 hold quarters of row r
    ss += __shfl_xor(ss, 1);
    ss += __shfl_xor(ss, 2);
    const float rbn = RBSCALE / sqrtf(ss);

    char* db = dst + (size_t)rb_loc * BLK64;
#pragma unroll
    for (int j = 0; j < 4; ++j) {
        bf16x8 v;
        float4 a = f[2 * j], b = f[2 * j + 1];
        v[0] = (__bf16)(a.x * rbn); v[1] = (__bf16)(a.y * rbn);
        v[2] = (__bf16)(a.z * rbn); v[3] = (__bf16)(a.w * rbn);
        v[4] = (__bf16)(b.x * rbn); v[5] = (__bf16)(b.y * rbn);
        v[6] = (__bf16)(b.z * rbn); v[7] = (__bf16)(b.w * rbn);
        *(bf16x8*)(db + (size_t)(q * 4 + j) * 1024 + (size_t)rr * 16) = v;
    }
}

template <bool MASKED>
__device__ __forceinline__ float tile_sum(const f32x16& a0, const f32x16& a1,
                                          int i00, int c) {
    float s = 0.f;
#pragma unroll
    for (int g = 0; g < 2; ++g) {
        const f32x16& a = g ? a1 : a0;
        int ib = i00 + g * 32;
#pragma unroll
        for (int r = 0; r < 16; ++r) {
            float ev = exp2f(a[r]);
            if (MASKED) {
                int i = ib + (r & 3) + 8 * (r >> 2);   // m74/m101 C/D row map
                int d = (c - i) & BMASK;               // (c-i) mod B
                s += (d > i) ? ev : 0.f;
            } else {
                s += ev;
            }
        }
    }
    return s;
}

// Exactly 1024 blocks (4/CU co-resident). Block b -> panel p=b&63, chunk s=b>>6:
// handles z0 tiles [8s, min(8s+8,cnt_p)) on P1 AND z1 tiles [8s,8s+8) on P2,
// sharing one register-resident 128x128 A panel. 256 threads = 4 waves:
// w>>1 = row half (64 rows), w&1 = col half (32 cols).
__global__ __launch_bounds__(256, 3)
void pair_kernel(const char* __restrict__ P1, const char* __restrict__ P2,
                 float* __restrict__ accg, float* __restrict__ out) {
    __shared__ __align__(16) __bf16 Bbuf[2][8192];   // 2 x 16 KB
    __shared__ float red[2][4];

    const int tid = threadIdx.x;
    const int b   = blockIdx.x;
    const int p   = b & 63;              // panel (decorrelated from chunk across CUs)
    const int s   = b >> 6;              // chunk 0..15

    const int i0  = 128 * p;
    const int e1  = (i0 > 128) ? i0 : 128;
    const int cnt = (p < 2) ? 128 : (130 - 2 * p);   // z0 tiles in this panel

    int n0 = cnt - 8 * s;                            // z0 tiles in this chunk
    n0 = (n0 < 0) ? 0 : ((n0 > 8) ? 8 : n0);
    const int L = n0 + 8;                            // + 8 z1 tiles

    // tile m -> (source, col origin, masked)
    auto tile_src = [&](int m) -> const char* { return (m < n0) ? P1 : P2; };
    auto tile_c0  = [&](int m) -> int {
        if (m < n0) {
            int k = 8 * s + m;
            int e = (k == 0) ? 64 : e1 + 64 * (k - 1);
            return (i0 + e) & BMASK;
        }
        return 64 * (8 * s + (m - n0));
    };
    auto tile_masked = [&](int m) -> bool {
        if (m >= n0) return false;
        int k = 8 * s + m;
        int e = (k == 0) ? 64 : e1 + 64 * (k - 1);
        return (e < i0 + 256) || (e > 8128);
    };

    const int w  = tid >> 6, lane = tid & 63;
    const int w2 = w >> 1, wc = w & 1;
    const int l  = lane & 31, h = lane >> 5;

    // ---- A panel -> registers: rows i0 + w2*64 + [0,64), k-major packed ----
    bf16x8 af[2][8];
    {
        const char* ap = P1 + (size_t)(p * 2 + w2) * BLK64;
#pragma unroll
        for (int g = 0; g < 2; ++g)
#pragma unroll
            for (int sc = 0; sc < 8; ++sc)
                af[g][sc] = *(const bf16x8*)(ap + (size_t)(sc * 2 + h) * 1024
                                                + (size_t)(g * 32 + l) * 16);
    }

    // ---- async stage: 16 KB tile, lane-linear (256 thr x 16 B x 4 rounds) ----
    auto stage = [&](int bufi, int m) {
        const char* gp = tile_src(m) + (size_t)(tile_c0(m) >> 6) * BLK64 + (size_t)tid * 16;
        char*       lp = (char*)&Bbuf[bufi][0] + (size_t)tid * 16;
#pragma unroll
        for (int r = 0; r < 4; ++r)
            __builtin_amdgcn_global_load_lds(
                (const __attribute__((address_space(1))) unsigned int*)(gp + r * 4096),
                (__attribute__((address_space(3))) unsigned int*)(lp + r * 4096),
                16, 0, 0);
    };

    const int i00 = i0 + w2 * 64 + 4 * h;   // epilogue row base for this lane
    const int cb  = wc * 32 + l;            // col offset within tile

    float s0 = 0.f, s1 = 0.f;
    stage(0, 0);
    int cur = 0;
    for (int m = 0; m < L; ++m) {
        __syncthreads();                     // buf[cur] staged; prev compute done
        if (m + 1 < L) stage(cur ^ 1, m + 1);

        f32x16 a0, a1;
#pragma unroll
        for (int r = 0; r < 16; ++r) { a0[r] = 0.f; a1[r] = 0.f; }

        const char* bb = (const char*)&Bbuf[cur][0] + (size_t)cb * 16 + (size_t)h * 1024;
#pragma unroll
        for (int sc = 0; sc < 8; ++sc) {
            bf16x8 bf = *(const bf16x8*)(bb + (size_t)sc * 2048);
            a0 = __builtin_amdgcn_mfma_f32_32x32x16_bf16(af[0][sc], bf, a0, 0, 0, 0);
            a1 = __builtin_amdgcn_mfma_f32_32x32x16_bf16(af[1][sc], bf, a1, 0, 0, 0);
        }

        int c = tile_c0(m) + cb;
        float ts = tile_masked(m) ? tile_sum<true >(a0, a1, i00, c)
                                  : tile_sum<false>(a0, a1, i00, c);
        if (m < n0) s0 += ts; else s1 += ts;
        cur ^= 1;
    }

#pragma unroll
    for (int o = 32; o > 0; o >>= 1) {
        s0 += __shfl_down(s0, o);
        s1 += __shfl_down(s1, o);
    }
    if (lane == 0) { red[0][w] = s0; red[1][w] = s1; }
    __syncthreads();
    if (tid == 0) {
        atomicAdd(&accg[0], red[0][0] + red[0][1] + red[0][2] + red[0][3]);
        atomicAdd(&accg[1], red[1][0] + red[1][1] + red[1][2] + red[1][3]);
        __threadfence();
        unsigned prev = atomicAdd((unsigned*)&accg[2], 1u);
        if (prev == (unsigned)(NBLOCKS - 1)) {
            float l1 = atomicAdd(&accg[0], 0.f);
            float l2 = atomicAdd(&accg[1], 0.f);
            out[0] = -logf(l1 / l2);
        }
    }
}

extern "C" void kernel_launch(void* const* d_in, const int* in_sizes, int n_in,
                              void* d_out, int out_size, void* d_ws, size_t ws_size,
                              hipStream_t stream) {
    (void)in_sizes; (void)n_in; (void)out_size; (void)ws_size;
    const float* e1 = (const float*)d_in[0];
    const float* e2 = (const float*)d_in[1];
    float* out = (float*)d_out;
    char*  ws  = (char*)d_ws;

    float* acc = (float*)ws;                       // 16 B: l1, l2, counter, pad
    char*  p1  = ws + 4096;                        // 2 MB packed E1
    char*  p2  = ws + 4096 + 2097152;              // 2 MB packed E2

    prep_kernel<<<dim3(256), dim3(256), 0, stream>>>(e1, e2, p1, p2, acc);
    pair_kernel<<<dim3(NBLOCKS), dim3(256), 0, stream>>>(p1, p2, acc, out);
}